// Round 1
// baseline (1256.717 us; speedup 1.0000x reference)
//
#include <hip/hip_runtime.h>

#define LN4 1.3862943611198906f

// ---------------------------------------------------------------------------
// Tiled gather-GEMM: out[n,d] = sum_k sum_c feat[nbr[n,k],c] * W[k,c,d]
// A-tile stored transposed in LDS so compute reads are float4 (b128).
// Each thread computes a 4x4 register tile. nbr value == N is the zero row.
// ---------------------------------------------------------------------------
template<int CIN, int COUT, int BM, int TX, int TY>
__global__ __launch_bounds__(TX*TY) void subconv_tiled(
    const float* __restrict__ feat, const int* __restrict__ nbr,
    const float* __restrict__ W, float* __restrict__ out, int N)
{
    constexpr int RM = 4, RN = 4;
    static_assert(TY * RM == BM, "BM mismatch");
    static_assert(TX * RN == COUT, "COUT mismatch");
    constexpr int BLK = TX * TY;
    constexpr int APITCH = BM + 4;      // multiple of 4 -> float4 aligned
    constexpr int WPITCH = COUT + 4;    // multiple of 4 -> float4 aligned

    __shared__ __align__(16) float As[CIN * APITCH];  // [c][r] transposed
    __shared__ __align__(16) float Ws[CIN * WPITCH];  // [c][d]
    __shared__ int idxS[BM * 27];

    const int t  = threadIdx.x;
    const int m0 = blockIdx.x * BM;

    // stage neighbor indices for the whole row tile
    for (int i = t; i < BM * 27; i += BLK) {
        int r = i / 27;
        int row = m0 + r;
        idxS[i] = (row < N) ? nbr[(size_t)row * 27 + (i - r * 27)] : N;
    }

    const int tx = t % TX, ty = t / TX;
    float acc[RM][RN] = {};

    for (int k = 0; k < 27; ++k) {
        __syncthreads();  // covers idxS (k=0) and previous compute
        // stage W[k] : CIN x COUT
        for (int i = t; i < CIN * COUT; i += BLK) {
            int r = i / COUT, c = i - r * COUT;
            Ws[r * WPITCH + c] = W[(size_t)k * CIN * COUT + i];
        }
        // stage gathered A tile (transposed): As[c][r] = feat[nbr[m0+r,k], c]
        for (int i = t; i < BM * CIN; i += BLK) {
            int r = i / CIN, c = i - r * CIN;
            int idx = idxS[r * 27 + k];
            float v = 0.0f;
            if (idx < N) v = feat[(size_t)idx * CIN + c];
            As[c * APITCH + r] = v;
        }
        __syncthreads();
        #pragma unroll 4
        for (int c = 0; c < CIN; ++c) {
            float4 av = *(const float4*)&As[c * APITCH + ty * RM];
            float4 wv = *(const float4*)&Ws[c * WPITCH + tx * RN];
            const float a[4] = {av.x, av.y, av.z, av.w};
            const float w[4] = {wv.x, wv.y, wv.z, wv.w};
            #pragma unroll
            for (int i = 0; i < RM; ++i)
                #pragma unroll
                for (int j = 0; j < RN; ++j)
                    acc[i][j] += a[i] * w[j];
        }
    }

    #pragma unroll
    for (int i = 0; i < RM; ++i) {
        int row = m0 + ty * RM + i;
        if (row < N) {
            float4 v = make_float4(acc[i][0], acc[i][1], acc[i][2], acc[i][3]);
            *(float4*)&out[(size_t)row * COUT + tx * RN] = v;
        }
    }
}

// ---------------------------------------------------------------------------
// Score conv (Cout=2) + softmax-threshold mask + ppn concat output.
// One wave per output row; W staged fully in LDS.
// ---------------------------------------------------------------------------
template<int CIN>
__global__ __launch_bounds__(256) void score_kernel(
    const float* __restrict__ y, const int* __restrict__ nbr,
    const float* __restrict__ Wsc,            // [27][CIN][2]
    const int* __restrict__ coords,           // [N][4]
    float* __restrict__ ppn,                  // [N][6]
    float* __restrict__ maskout,              // [N]
    int N)
{
    __shared__ float Ws[27 * CIN * 2];
    for (int i = threadIdx.x; i < 27 * CIN * 2; i += 256) Ws[i] = Wsc[i];
    __syncthreads();

    const int wave = threadIdx.x >> 6;
    const int lane = threadIdx.x & 63;
    const int n = blockIdx.x * 4 + wave;
    if (n >= N) return;

    float a0 = 0.0f, a1 = 0.0f;
    for (int e = lane; e < 27 * CIN; e += 64) {
        int k = e / CIN, c = e - k * CIN;
        int idx = nbr[(size_t)n * 27 + k];
        if (idx < N) {
            float v = y[(size_t)idx * CIN + c];
            a0 += v * Ws[2 * e];
            a1 += v * Ws[2 * e + 1];
        }
    }
    #pragma unroll
    for (int off = 32; off > 0; off >>= 1) {
        a0 += __shfl_down(a0, off);
        a1 += __shfl_down(a1, off);
    }
    if (lane == 0) {
        ppn[(size_t)n * 6 + 0] = (float)coords[(size_t)n * 4 + 0];
        ppn[(size_t)n * 6 + 1] = (float)coords[(size_t)n * 4 + 1];
        ppn[(size_t)n * 6 + 2] = (float)coords[(size_t)n * 4 + 2];
        ppn[(size_t)n * 6 + 3] = (float)coords[(size_t)n * 4 + 3];
        ppn[(size_t)n * 6 + 4] = a0;
        ppn[(size_t)n * 6 + 5] = a1;
        // softmax(s)[1] > 0.8  <=>  s1 - s0 > ln(4)
        maskout[n] = (a1 - a0 > LN4) ? 1.0f : 0.0f;
    }
}

// ---------------------------------------------------------------------------
// feat_scaled[j,:] = feat[j,:] * mask[parent[j]]
// ---------------------------------------------------------------------------
template<int C>
__global__ __launch_bounds__(256) void apply_att(
    const float* __restrict__ feat, const float* __restrict__ mask,
    const int* __restrict__ parent, float* __restrict__ out, int total)
{
    int i = blockIdx.x * 256 + threadIdx.x;
    if (i < total) {
        int j = i / C;
        out[i] = feat[i] * mask[parent[j]];
    }
}

// ---------------------------------------------------------------------------
// Fused final heads: points[n, 0:10] = [pixel(3) | scores(2) | type(5)]
// from z (CIN=16) with concatenated weights staged in LDS. Wave per row.
// ---------------------------------------------------------------------------
__global__ __launch_bounds__(256) void points_kernel(
    const float* __restrict__ z, const int* __restrict__ nbr,
    const float* __restrict__ W3p, const float* __restrict__ W3s,
    const float* __restrict__ W3t, float* __restrict__ points, int N)
{
    __shared__ float Ws[27 * 16 * 10];
    for (int i = threadIdx.x; i < 27 * 16 * 3; i += 256) {
        int kc = i / 3, j = i - kc * 3;
        Ws[kc * 10 + j] = W3p[i];
    }
    for (int i = threadIdx.x; i < 27 * 16 * 2; i += 256) {
        int kc = i / 2, j = i - kc * 2;
        Ws[kc * 10 + 3 + j] = W3s[i];
    }
    for (int i = threadIdx.x; i < 27 * 16 * 5; i += 256) {
        int kc = i / 5, j = i - kc * 5;
        Ws[kc * 10 + 5 + j] = W3t[i];
    }
    __syncthreads();

    const int wave = threadIdx.x >> 6;
    const int lane = threadIdx.x & 63;
    const int n = blockIdx.x * 4 + wave;
    if (n >= N) return;

    float acc[10] = {};
    for (int e = lane; e < 27 * 16; e += 64) {
        int k = e >> 4, c = e & 15;
        int idx = nbr[(size_t)n * 27 + k];
        if (idx < N) {
            float v = z[(size_t)idx * 16 + c];
            #pragma unroll
            for (int d = 0; d < 10; ++d) acc[d] += v * Ws[e * 10 + d];
        }
    }
    #pragma unroll
    for (int d = 0; d < 10; ++d) {
        #pragma unroll
        for (int off = 32; off > 0; off >>= 1) acc[d] += __shfl_down(acc[d], off);
    }
    if (lane == 0) {
        #pragma unroll
        for (int d = 0; d < 10; ++d) points[(size_t)n * 10 + d] = acc[d];
    }
}

// ---------------------------------------------------------------------------
extern "C" void kernel_launch(void* const* d_in, const int* in_sizes, int n_in,
                              void* d_out, int out_size, void* d_ws, size_t ws_size,
                              hipStream_t stream)
{
    const float* feat1 = (const float*)d_in[0];
    const float* feat2 = (const float*)d_in[1];
    const float* feat3 = (const float*)d_in[2];
    const float* W1    = (const float*)d_in[3];
    const float* W1s   = (const float*)d_in[4];
    const float* W2    = (const float*)d_in[5];
    const float* W2s   = (const float*)d_in[6];
    const float* W3    = (const float*)d_in[7];
    const float* W3p   = (const float*)d_in[8];
    const float* W3s   = (const float*)d_in[9];
    const float* W3t   = (const float*)d_in[10];
    const int* nbr1    = (const int*)d_in[11];
    const int* nbr2    = (const int*)d_in[12];
    const int* nbr3    = (const int*)d_in[13];
    const int* parent2 = (const int*)d_in[14];
    const int* parent3 = (const int*)d_in[15];
    const int* coords1 = (const int*)d_in[16];
    const int* coords2 = (const int*)d_in[17];

    const int N1 = in_sizes[0] / 80;
    const int N2 = in_sizes[1] / 48;
    const int N3 = in_sizes[2] / 16;

    float* out = (float*)d_out;
    float* o_points = out;                              // [N3,10]
    float* o_ppn1   = o_points + (size_t)N3 * 10;       // [N1,6]
    float* o_ppn2   = o_ppn1 + (size_t)N1 * 6;          // [N2,6]
    float* o_mask1  = o_ppn2 + (size_t)N2 * 6;          // [N1]
    float* o_mask2  = o_mask1 + (size_t)N1;             // [N2]

    float* ws  = (float*)d_ws;
    float* y1  = ws;                                    // N1*80
    float* f2s = y1 + (size_t)N1 * 80;                  // N2*48
    float* y2  = f2s + (size_t)N2 * 48;                 // N2*48
    float* f3s = y2 + (size_t)N2 * 48;                  // N3*16
    float* z   = f3s + (size_t)N3 * 16;                 // N3*16

    // --- Level 1 (coarse, C=80) ---
    {
        dim3 grid((N1 + 63) / 64);
        subconv_tiled<80, 80, 64, 20, 16><<<grid, 320, 0, stream>>>(feat1, nbr1, W1, y1, N1);
        dim3 g2((N1 + 3) / 4);
        score_kernel<80><<<g2, 256, 0, stream>>>(y1, nbr1, W1s, coords1, o_ppn1, o_mask1, N1);
    }
    // --- Level 2 (mid, C=48) ---
    {
        int tot = N2 * 48;
        apply_att<48><<<dim3((tot + 255) / 256), 256, 0, stream>>>(feat2, o_mask1, parent2, f2s, tot);
        dim3 grid((N2 + 63) / 64);
        subconv_tiled<48, 48, 64, 12, 16><<<grid, 192, 0, stream>>>(f2s, nbr2, W2, y2, N2);
        dim3 g2((N2 + 3) / 4);
        score_kernel<48><<<g2, 256, 0, stream>>>(y2, nbr2, W2s, coords2, o_ppn2, o_mask2, N2);
    }
    // --- Level 3 (fine, C=16) ---
    {
        int tot = N3 * 16;
        apply_att<16><<<dim3((tot + 255) / 256), 256, 0, stream>>>(feat3, o_mask2, parent3, f3s, tot);
        dim3 grid((N3 + 63) / 64);
        subconv_tiled<16, 16, 64, 4, 16><<<grid, 64, 0, stream>>>(f3s, nbr3, W3, z, N3);
        dim3 g2((N3 + 3) / 4);
        points_kernel<<<g2, 256, 0, stream>>>(z, nbr3, W3p, W3s, W3t, o_points, N3);
    }
}

// Round 2
// 745.349 us; speedup vs baseline: 1.6861x; 1.6861x over previous
//
#include <hip/hip_runtime.h>

typedef _Float16 f16;
typedef _Float16 f16x8 __attribute__((ext_vector_type(8)));
typedef float f32x4 __attribute__((ext_vector_type(4)));

#define LN4 1.3862943611198906f

// ===========================================================================
// Prep: split fp32 W[27][CIN][COUT] -> f16 hi/lo, transposed+padded:
// WT[d][tap*CIN+c], d in [0,CPAD), tap in [0,28) (tap 27 and d>=COUT are 0).
// ===========================================================================
__global__ __launch_bounds__(256) void split_wt_kernel(
    const float* __restrict__ W, f16* __restrict__ h, f16* __restrict__ l,
    int CIN, int COUT, int CPAD)
{
    int i = blockIdx.x * 256 + threadIdx.x;
    int total = CPAD * 28 * CIN;
    if (i >= total) return;
    int d = i / (28 * CIN);
    int rem = i - d * (28 * CIN);
    int tap = rem / CIN;
    int c = rem - tap * CIN;
    float v = 0.f;
    if (d < COUT && tap < 27) v = W[((size_t)(tap * CIN + c)) * COUT + d];
    f16 hi = (f16)v;
    h[i] = hi;
    l[i] = (f16)(v - (float)hi);
}

// Combined points-head weights: d 0..2 <- W3p, 3..4 <- W3s, 5..9 <- W3t.
__global__ __launch_bounds__(256) void split_wpts_kernel(
    const float* __restrict__ Wp, const float* __restrict__ Ws,
    const float* __restrict__ Wt, f16* __restrict__ h, f16* __restrict__ l)
{
    int i = blockIdx.x * 256 + threadIdx.x;
    const int total = 16 * 28 * 16;
    if (i >= total) return;
    int d = i / (28 * 16);
    int rem = i - d * (28 * 16);
    int tap = rem / 16;
    int c = rem - tap * 16;
    float v = 0.f;
    if (tap < 27) {
        int kc = tap * 16 + c;
        if (d < 3)       v = Wp[(size_t)kc * 3 + d];
        else if (d < 5)  v = Ws[(size_t)kc * 2 + (d - 3)];
        else if (d < 10) v = Wt[(size_t)kc * 5 + (d - 5)];
    }
    f16 hi = (f16)v;
    h[i] = hi;
    l[i] = (f16)(v - (float)hi);
}

// Split features (optionally masked by mask[parent[row]]) into f16 hi/lo.
__global__ __launch_bounds__(256) void split_feat_kernel(
    const float* __restrict__ f, const float* __restrict__ mask,
    const int* __restrict__ parent, f16* __restrict__ h, f16* __restrict__ l,
    int C, int total)
{
    int i = blockIdx.x * 256 + threadIdx.x;
    if (i >= total) return;
    float v = f[i];
    if (mask) v *= mask[parent[i / C]];
    f16 hi = (f16)v;
    h[i] = hi;
    l[i] = (f16)(v - (float)hi);
}

// ppn concat + threshold mask from raw scores.
__global__ __launch_bounds__(256) void ppn_finalize_kernel(
    const int* __restrict__ coords, const float* __restrict__ s,
    float* __restrict__ ppn, float* __restrict__ mask, int N)
{
    int n = blockIdx.x * 256 + threadIdx.x;
    if (n >= N) return;
    float s0 = s[(size_t)n * 2 + 0], s1 = s[(size_t)n * 2 + 1];
    ppn[(size_t)n * 6 + 0] = (float)coords[(size_t)n * 4 + 0];
    ppn[(size_t)n * 6 + 1] = (float)coords[(size_t)n * 4 + 1];
    ppn[(size_t)n * 6 + 2] = (float)coords[(size_t)n * 4 + 2];
    ppn[(size_t)n * 6 + 3] = (float)coords[(size_t)n * 4 + 3];
    ppn[(size_t)n * 6 + 4] = s0;
    ppn[(size_t)n * 6 + 5] = s1;
    mask[n] = (s1 - s0 > LN4) ? 1.0f : 0.0f;
}

// ===========================================================================
// MFMA gather-conv. out[n, d] = sum_{tap,c} feat[nbr[n,tap], c] * W[tap][c][d]
// f16-split 3-term (hi*hi + lo*hi + hi*lo), fp32 accumulate.
// BM=128 rows/block, 256 threads (4 waves x 2 M-bands), 2 taps per K-slab.
// A LDS layout [r][tapsub*CIN + c] (k-contiguous, MFMA A layout).
// B LDS layout [d][k] from pre-transposed WT.
// SPLIT_OUT: write f16 hi/lo (intermediate y/z). Else fp32, cols < OUTC.
// ===========================================================================
template<int CIN, int NCT, int OUTC, bool SPLIT_OUT>
__global__ __launch_bounds__(256) void mfma_conv(
    const f16* __restrict__ fh, const f16* __restrict__ fl,
    const int* __restrict__ nbr,
    const f16* __restrict__ wth, const f16* __restrict__ wtl,
    float* __restrict__ out_f32, f16* __restrict__ oh, f16* __restrict__ ol,
    int N)
{
    constexpr int BM = 128;
    constexpr int K2 = 2 * CIN;            // K per 2-tap slab (f16 elems)
    constexpr int KB = K2 / 32;            // MFMA K-blocks per slab
    constexpr int COUT = NCT * 16;
    static_assert(K2 % 32 == 0 && CIN % 8 == 0, "bad CIN");

    __shared__ __align__(16) f16 Ah[BM * K2];
    __shared__ __align__(16) f16 Al[BM * K2];
    __shared__ __align__(16) f16 Bh[COUT * K2];
    __shared__ __align__(16) f16 Bl[COUT * K2];

    const int t = threadIdx.x;
    const int lane = t & 63;
    const int wv = t >> 6;
    const int l16 = lane & 15;
    const int quad = lane >> 4;
    const int m0 = blockIdx.x * BM;

    f32x4 acc[2][NCT];
    #pragma unroll
    for (int b = 0; b < 2; ++b)
        #pragma unroll
        for (int ct = 0; ct < NCT; ++ct)
            acc[b][ct] = (f32x4){0.f, 0.f, 0.f, 0.f};

    constexpr int KCH = K2 / 8;            // 16B chunks per A row-slab
    constexpr int CCH = CIN / 8;           // chunks per tap
    constexpr int ACH = BM * KCH;          // A chunks per array
    constexpr int WCH = COUT * KCH;        // W chunks per array

    for (int p = 0; p < 14; ++p) {
        __syncthreads();
        // stage W slab
        for (int i = t; i < WCH; i += 256) {
            int d = i / KCH;
            int ko = (i - d * KCH) * 8;
            *(f16x8*)&Bh[d * K2 + ko] =
                *(const f16x8*)&wth[(size_t)d * (28 * CIN) + p * K2 + ko];
            *(f16x8*)&Bl[d * K2 + ko] =
                *(const f16x8*)&wtl[(size_t)d * (28 * CIN) + p * K2 + ko];
        }
        // stage gathered A slab (2 taps)
        for (int i = t; i < ACH; i += 256) {
            int r = i / KCH;
            int w = i - r * KCH;
            int tapsub = w / CCH;
            int co = (w - tapsub * CCH) * 8;
            int tap = 2 * p + tapsub;
            int row = m0 + r;
            int idx = (row < N && tap < 27) ? nbr[(size_t)row * 27 + tap] : -1;
            f16x8 vh = {}, vl = {};
            if (idx >= 0 && idx < N) {
                vh = *(const f16x8*)&fh[(size_t)idx * CIN + co];
                vl = *(const f16x8*)&fl[(size_t)idx * CIN + co];
            }
            *(f16x8*)&Ah[r * K2 + tapsub * CIN + co] = vh;
            *(f16x8*)&Al[r * K2 + tapsub * CIN + co] = vl;
        }
        __syncthreads();
        // compute
        #pragma unroll
        for (int kb = 0; kb < KB; ++kb) {
            const int ko = kb * 32 + quad * 8;
            f16x8 a_h[2], a_l[2];
            #pragma unroll
            for (int b = 0; b < 2; ++b) {
                int mrow = (2 * wv + b) * 16 + l16;
                a_h[b] = *(const f16x8*)&Ah[mrow * K2 + ko];
                a_l[b] = *(const f16x8*)&Al[mrow * K2 + ko];
            }
            #pragma unroll
            for (int ct = 0; ct < NCT; ++ct) {
                int drow = ct * 16 + l16;
                f16x8 b_h = *(const f16x8*)&Bh[drow * K2 + ko];
                f16x8 b_l = *(const f16x8*)&Bl[drow * K2 + ko];
                #pragma unroll
                for (int b = 0; b < 2; ++b) {
                    acc[b][ct] = __builtin_amdgcn_mfma_f32_16x16x32_f16(a_h[b], b_h, acc[b][ct], 0, 0, 0);
                    acc[b][ct] = __builtin_amdgcn_mfma_f32_16x16x32_f16(a_l[b], b_h, acc[b][ct], 0, 0, 0);
                    acc[b][ct] = __builtin_amdgcn_mfma_f32_16x16x32_f16(a_h[b], b_l, acc[b][ct], 0, 0, 0);
                }
            }
        }
    }

    // epilogue: D row = quad*4+reg, col = lane&15 (within 16x16 tile)
    #pragma unroll
    for (int b = 0; b < 2; ++b) {
        #pragma unroll
        for (int ct = 0; ct < NCT; ++ct) {
            int col = ct * 16 + l16;
            #pragma unroll
            for (int r = 0; r < 4; ++r) {
                int row = m0 + (2 * wv + b) * 16 + quad * 4 + r;
                if (row < N) {
                    float v = acc[b][ct][r];
                    if (SPLIT_OUT) {
                        f16 hi = (f16)v;
                        oh[(size_t)row * COUT + col] = hi;
                        ol[(size_t)row * COUT + col] = (f16)(v - (float)hi);
                    } else if (col < OUTC) {
                        out_f32[(size_t)row * OUTC + col] = v;
                    }
                }
            }
        }
    }
}

// ===========================================================================
extern "C" void kernel_launch(void* const* d_in, const int* in_sizes, int n_in,
                              void* d_out, int out_size, void* d_ws, size_t ws_size,
                              hipStream_t stream)
{
    const float* feat1 = (const float*)d_in[0];
    const float* feat2 = (const float*)d_in[1];
    const float* feat3 = (const float*)d_in[2];
    const float* W1    = (const float*)d_in[3];
    const float* W1s   = (const float*)d_in[4];
    const float* W2    = (const float*)d_in[5];
    const float* W2s   = (const float*)d_in[6];
    const float* W3    = (const float*)d_in[7];
    const float* W3p   = (const float*)d_in[8];
    const float* W3s   = (const float*)d_in[9];
    const float* W3t   = (const float*)d_in[10];
    const int* nbr1    = (const int*)d_in[11];
    const int* nbr2    = (const int*)d_in[12];
    const int* nbr3    = (const int*)d_in[13];
    const int* parent2 = (const int*)d_in[14];
    const int* parent3 = (const int*)d_in[15];
    const int* coords1 = (const int*)d_in[16];
    const int* coords2 = (const int*)d_in[17];

    const int N1 = in_sizes[0] / 80;
    const int N2 = in_sizes[1] / 48;
    const int N3 = in_sizes[2] / 16;

    float* out = (float*)d_out;
    float* o_points = out;                              // [N3,10]
    float* o_ppn1   = o_points + (size_t)N3 * 10;       // [N1,6]
    float* o_ppn2   = o_ppn1 + (size_t)N1 * 6;          // [N2,6]
    float* o_mask1  = o_ppn2 + (size_t)N2 * 6;          // [N1]
    float* o_mask2  = o_mask1 + (size_t)N1;             // [N2]

    // ---- workspace layout (256B aligned bump allocator) ----
    char* wp = (char*)d_ws;
    auto alloc = [&](size_t bytes) -> char* {
        char* r = wp; wp += (bytes + 255) & ~(size_t)255; return r;
    };
    // weight buffers (persistent)
    f16* WT1h  = (f16*)alloc((size_t)80 * 28 * 80 * 2);
    f16* WT1l  = (f16*)alloc((size_t)80 * 28 * 80 * 2);
    f16* WT1sh = (f16*)alloc((size_t)16 * 28 * 80 * 2);
    f16* WT1sl = (f16*)alloc((size_t)16 * 28 * 80 * 2);
    f16* WT2h  = (f16*)alloc((size_t)48 * 28 * 48 * 2);
    f16* WT2l  = (f16*)alloc((size_t)48 * 28 * 48 * 2);
    f16* WT2sh = (f16*)alloc((size_t)16 * 28 * 48 * 2);
    f16* WT2sl = (f16*)alloc((size_t)16 * 28 * 48 * 2);
    f16* WT3h  = (f16*)alloc((size_t)16 * 28 * 16 * 2);
    f16* WT3l  = (f16*)alloc((size_t)16 * 28 * 16 * 2);
    f16* WTph  = (f16*)alloc((size_t)16 * 28 * 16 * 2);
    f16* WTpl  = (f16*)alloc((size_t)16 * 28 * 16 * 2);
    // scores
    float* s1 = (float*)alloc((size_t)N1 * 2 * 4);
    float* s2 = (float*)alloc((size_t)N2 * 2 * 4);
    // arena A: masked input features (f16), reused across levels
    size_t szF1 = (size_t)N1 * 80 * 2, szF2 = (size_t)N2 * 48 * 2, szF3 = (size_t)N3 * 16 * 2;
    size_t maxA = szF1 > szF2 ? szF1 : szF2; if (szF3 > maxA) maxA = szF3;
    f16* arAh = (f16*)alloc(maxA);
    f16* arAl = (f16*)alloc(maxA);
    // arena B: conv outputs y/z (f16), reused across levels
    f16* arBh = (f16*)alloc(maxA);
    f16* arBl = (f16*)alloc(maxA);

    auto cdiv = [](int a, int b) { return (a + b - 1) / b; };

    // ---- weight prep ----
    split_wt_kernel<<<cdiv(80 * 28 * 80, 256), 256, 0, stream>>>(W1, WT1h, WT1l, 80, 80, 80);
    split_wt_kernel<<<cdiv(16 * 28 * 80, 256), 256, 0, stream>>>(W1s, WT1sh, WT1sl, 80, 2, 16);
    split_wt_kernel<<<cdiv(48 * 28 * 48, 256), 256, 0, stream>>>(W2, WT2h, WT2l, 48, 48, 48);
    split_wt_kernel<<<cdiv(16 * 28 * 48, 256), 256, 0, stream>>>(W2s, WT2sh, WT2sl, 48, 2, 16);
    split_wt_kernel<<<cdiv(16 * 28 * 16, 256), 256, 0, stream>>>(W3, WT3h, WT3l, 16, 16, 16);
    split_wpts_kernel<<<cdiv(16 * 28 * 16, 256), 256, 0, stream>>>(W3p, W3s, W3t, WTph, WTpl);

    // ---- level 1 (coarse, C=80) ----
    split_feat_kernel<<<cdiv(N1 * 80, 256), 256, 0, stream>>>(
        feat1, nullptr, nullptr, arAh, arAl, 80, N1 * 80);
    mfma_conv<80, 5, 80, true><<<cdiv(N1, 128), 256, 0, stream>>>(
        arAh, arAl, nbr1, WT1h, WT1l, nullptr, arBh, arBl, N1);
    mfma_conv<80, 1, 2, false><<<cdiv(N1, 128), 256, 0, stream>>>(
        arBh, arBl, nbr1, WT1sh, WT1sl, s1, nullptr, nullptr, N1);
    ppn_finalize_kernel<<<cdiv(N1, 256), 256, 0, stream>>>(coords1, s1, o_ppn1, o_mask1, N1);

    // ---- level 2 (mid, C=48) ----
    split_feat_kernel<<<cdiv(N2 * 48, 256), 256, 0, stream>>>(
        feat2, o_mask1, parent2, arAh, arAl, 48, N2 * 48);
    mfma_conv<48, 3, 48, true><<<cdiv(N2, 128), 256, 0, stream>>>(
        arAh, arAl, nbr2, WT2h, WT2l, nullptr, arBh, arBl, N2);
    mfma_conv<48, 1, 2, false><<<cdiv(N2, 128), 256, 0, stream>>>(
        arBh, arBl, nbr2, WT2sh, WT2sl, s2, nullptr, nullptr, N2);
    ppn_finalize_kernel<<<cdiv(N2, 256), 256, 0, stream>>>(coords2, s2, o_ppn2, o_mask2, N2);

    // ---- level 3 (fine, C=16) ----
    split_feat_kernel<<<cdiv(N3 * 16, 256), 256, 0, stream>>>(
        feat3, o_mask2, parent3, arAh, arAl, 16, N3 * 16);
    mfma_conv<16, 1, 16, true><<<cdiv(N3, 128), 256, 0, stream>>>(
        arAh, arAl, nbr3, WT3h, WT3l, nullptr, arBh, arBl, N3);
    mfma_conv<16, 1, 10, false><<<cdiv(N3, 128), 256, 0, stream>>>(
        arBh, arBl, nbr3, WTph, WTpl, o_points, nullptr, nullptr, N3);
}

// Round 3
// 560.489 us; speedup vs baseline: 2.2422x; 1.3298x over previous
//
#include <hip/hip_runtime.h>

typedef _Float16 f16;
typedef _Float16 f16x8 __attribute__((ext_vector_type(8)));
typedef float f32x4 __attribute__((ext_vector_type(4)));

#define LN4 1.3862943611198906f

__device__ __forceinline__ void gl_lds16(const void* g, void* l) {
    typedef unsigned int u32;
    __builtin_amdgcn_global_load_lds(
        (const __attribute__((address_space(1))) u32*)(g),
        (__attribute__((address_space(3))) u32*)(l), 16, 0, 0);
}

// ===========================================================================
// Weight prep: fp32 W[27][CIN][COUT] -> combined f16 hi/lo, transposed:
// WT[d][tap][ h(CIN f16) | l(CIN f16) ], d<CPAD, tap<28 (tap27 & d>=COUT = 0)
// ===========================================================================
__device__ void prep_one(int gid, int gsz, const float* __restrict__ W,
                         f16* __restrict__ dst, int CIN, int COUT, int CPAD)
{
    int total = CPAD * 28 * CIN;
    for (int i = gid; i < total; i += gsz) {
        int d = i / (28 * CIN);
        int rem = i - d * (28 * CIN);
        int tap = rem / CIN;
        int c = rem - tap * CIN;
        float v = (d < COUT && tap < 27) ? W[(size_t)(tap * CIN + c) * COUT + d] : 0.f;
        f16 h = (f16)v;
        size_t base = (size_t)d * (28 * 2 * CIN) + (size_t)tap * (2 * CIN);
        dst[base + c] = h;
        dst[base + CIN + c] = (f16)(v - (float)h);
    }
}

__device__ void prep_pts(int gid, int gsz, const float* __restrict__ Wp,
                         const float* __restrict__ Ws, const float* __restrict__ Wt,
                         f16* __restrict__ dst)
{
    const int CIN = 16, CPAD = 16;
    int total = CPAD * 28 * CIN;
    for (int i = gid; i < total; i += gsz) {
        int d = i / (28 * CIN);
        int rem = i - d * (28 * CIN);
        int tap = rem / CIN;
        int c = rem - tap * CIN;
        float v = 0.f;
        if (tap < 27) {
            int kc = tap * CIN + c;
            if (d < 3)       v = Wp[(size_t)kc * 3 + d];
            else if (d < 5)  v = Ws[(size_t)kc * 2 + (d - 3)];
            else if (d < 10) v = Wt[(size_t)kc * 5 + (d - 5)];
        }
        f16 h = (f16)v;
        size_t base = (size_t)d * (28 * 2 * CIN) + (size_t)tap * (2 * CIN);
        dst[base + c] = h;
        dst[base + CIN + c] = (f16)(v - (float)h);
    }
}

__global__ __launch_bounds__(256) void prep_all_kernel(
    const float* W1, f16* WT1, const float* W1s, f16* WT1s,
    const float* W2, f16* WT2, const float* W2s, f16* WT2s,
    const float* W3, f16* WT3,
    const float* W3p, const float* W3s, const float* W3t, f16* WTp)
{
    int gid = blockIdx.x * 256 + threadIdx.x;
    int gsz = gridDim.x * 256;
    prep_one(gid, gsz, W1, WT1, 80, 80, 80);
    prep_one(gid, gsz, W1s, WT1s, 80, 2, 16);
    prep_one(gid, gsz, W2, WT2, 48, 48, 48);
    prep_one(gid, gsz, W2s, WT2s, 48, 2, 16);
    prep_one(gid, gsz, W3, WT3, 16, 16, 16);
    prep_pts(gid, gsz, W3p, W3s, W3t, WTp);
}

// ===========================================================================
// Feature split: fp32 (optionally masked) -> combined f16 rows [h|l],
// plus zero-sentinel row at n == N.
// ===========================================================================
template<int CIN>
__global__ __launch_bounds__(256) void split_feat_kernel(
    const float* __restrict__ f, const float* __restrict__ mask,
    const int* __restrict__ parent, f16* __restrict__ Fc, int N)
{
    int i = blockIdx.x * 256 + threadIdx.x;
    if (i >= (N + 1) * CIN) return;
    int n = i / CIN;
    int c = i - n * CIN;
    float v = 0.f;
    if (n < N) {
        v = f[i];
        if (mask != nullptr) v *= mask[parent[n]];
    }
    f16 h = (f16)v;
    Fc[(size_t)n * (2 * CIN) + c] = h;
    Fc[(size_t)n * (2 * CIN) + CIN + c] = (f16)(v - (float)h);
}

__global__ __launch_bounds__(256) void ppn_finalize_kernel(
    const int* __restrict__ coords, const float* __restrict__ s,
    float* __restrict__ ppn, float* __restrict__ mask, int N)
{
    int n = blockIdx.x * 256 + threadIdx.x;
    if (n >= N) return;
    float s0 = s[(size_t)n * 2 + 0], s1 = s[(size_t)n * 2 + 1];
    ppn[(size_t)n * 6 + 0] = (float)coords[(size_t)n * 4 + 0];
    ppn[(size_t)n * 6 + 1] = (float)coords[(size_t)n * 4 + 1];
    ppn[(size_t)n * 6 + 2] = (float)coords[(size_t)n * 4 + 2];
    ppn[(size_t)n * 6 + 3] = (float)coords[(size_t)n * 4 + 3];
    ppn[(size_t)n * 6 + 4] = s0;
    ppn[(size_t)n * 6 + 5] = s1;
    mask[n] = (s1 - s0 > LN4) ? 1.0f : 0.0f;
}

// ===========================================================================
// MFMA gather-conv, f16-split 3-term, global_load_lds staging.
// F: (N+1) combined rows [h|l] (row N = zeros, sentinel for nbr==N).
// WT: [CPAD=NCT*16][28 taps][h|l].  2 taps per K-slab, 14 slabs.
// LDS rows padded by one 16B chunk (skipped via zero-row source) so
// fragment b128 reads are conflict-free while staging stays chunk-linear.
// ===========================================================================
template<int CIN, int NCT, int NWAVES, int OUTC, bool SPLIT_OUT>
__global__ __launch_bounds__(NWAVES * 64) void mfma_conv(
    const f16* __restrict__ F, const int* __restrict__ nbr,
    const f16* __restrict__ WT, float* __restrict__ out_f32,
    f16* __restrict__ oc, int N, int nTiles)
{
    constexpr int BM = NWAVES * 16;
    constexpr int BLK = NWAVES * 64;
    constexpr int COUT = NCT * 16;
    constexpr int CC = CIN / 4;             // 16B chunks per tap-row (h+l)
    constexpr int PCH = 2 * CC + 1;         // chunks per padded LDS row
    constexpr int PB = PCH * 16;            // LDS row pitch bytes (≡16 mod 128)
    constexpr int ROWB = 4 * CIN;           // F row bytes (h+l)
    constexpr int KB = CIN / 16;            // K32 MFMA blocks per 2-tap slab
    constexpr int A_TOT = BM * PCH;         // multiple of 64 by construction
    constexpr int B_TOT = COUT * PCH;
    constexpr int B_PAD = ((B_TOT + 63) / 64) * 64;
    constexpr int A_IT = (A_TOT + BLK - 1) / BLK;
    constexpr int B_IT = (B_PAD + BLK - 1) / BLK;

    __shared__ __align__(16) f16 AS[A_TOT * 8];
    __shared__ __align__(16) f16 BS[B_PAD * 8];

    const int t = threadIdx.x;
    const int lane = t & 63;
    const int l16 = lane & 15;
    const int quad = lane >> 4;
    const int band = t >> 6;

    // XCD-contiguous swizzle: XCD x gets tile range [x*q8, (x+1)*q8)
    int q8 = (nTiles + 7) >> 3;
    int tile = (blockIdx.x & 7) * q8 + (blockIdx.x >> 3);
    if (tile >= nTiles) return;
    const int m0 = tile * BM;

    f32x4 acc[NCT];
    #pragma unroll
    for (int ct = 0; ct < NCT; ++ct) acc[ct] = (f32x4){0.f, 0.f, 0.f, 0.f};

    for (int p = 0; p < 14; ++p) {
        __syncthreads();
        // ---- stage B slab (2 taps, all d) via direct-to-LDS ----
        #pragma unroll
        for (int j = 0; j < B_IT; ++j) {
            int i = t + j * BLK;
            if (i >= B_PAD) continue;            // full-wave granularity
            int ii = i < B_TOT ? i : B_TOT - 1;
            int d = ii / PCH;
            int w = ii - d * PCH;
            int wc = w < 2 * CC ? w : 2 * CC - 1;  // pad chunk -> junk (never read)
            const char* src = (const char*)WT + (size_t)d * (28 * ROWB)
                              + (size_t)p * (2 * ROWB) + (size_t)wc * 16;
            gl_lds16(src, (char*)BS + (size_t)i * 16);
        }
        // ---- stage gathered A slab (2 taps) via direct-to-LDS ----
        #pragma unroll
        for (int j = 0; j < A_IT; ++j) {
            int i = t + j * BLK;
            if (i >= A_TOT) continue;            // full-wave granularity
            int r = i / PCH;
            int w = i - r * PCH;
            int ts = w >= CC;
            int wp = w - (ts ? CC : 0);
            bool padc = (w == 2 * CC);
            if (padc) wp = 0;
            int row = m0 + r;
            int tap = 2 * p + ts;
            int idx = N;                          // sentinel zero row
            if (!padc && row < N && tap < 27) idx = nbr[(size_t)row * 27 + tap];
            const char* src = (const char*)F + (size_t)idx * ROWB + (size_t)wp * 16;
            gl_lds16(src, (char*)AS + (size_t)i * 16);
        }
        __syncthreads();
        // ---- compute ----
        #pragma unroll
        for (int kb = 0; kb < KB; ++kb) {
            int ko = kb * 32 + quad * 8;          // logical k in [0, 2*CIN)
            int ts2 = ko >= CIN;
            int c2 = ko - ts2 * CIN;
            int aoff = (band * 16 + l16) * PB + ts2 * ROWB + 2 * c2;
            f16x8 a_h = *(const f16x8*)((const char*)AS + aoff);
            f16x8 a_l = *(const f16x8*)((const char*)AS + aoff + 2 * CIN);
            #pragma unroll
            for (int ct = 0; ct < NCT; ++ct) {
                int boff = (ct * 16 + l16) * PB + ts2 * ROWB + 2 * c2;
                f16x8 b_h = *(const f16x8*)((const char*)BS + boff);
                f16x8 b_l = *(const f16x8*)((const char*)BS + boff + 2 * CIN);
                acc[ct] = __builtin_amdgcn_mfma_f32_16x16x32_f16(a_h, b_h, acc[ct], 0, 0, 0);
                acc[ct] = __builtin_amdgcn_mfma_f32_16x16x32_f16(a_l, b_h, acc[ct], 0, 0, 0);
                acc[ct] = __builtin_amdgcn_mfma_f32_16x16x32_f16(a_h, b_l, acc[ct], 0, 0, 0);
            }
        }
    }

    // ---- epilogue: D row = quad*4+reg, col = lane&15 ----
    #pragma unroll
    for (int ct = 0; ct < NCT; ++ct) {
        int col = ct * 16 + l16;
        #pragma unroll
        for (int r = 0; r < 4; ++r) {
            int row = m0 + band * 16 + quad * 4 + r;
            if (SPLIT_OUT) {
                if (row < N) {
                    float v = acc[ct][r];
                    f16 h = (f16)v;
                    oc[(size_t)row * (2 * COUT) + col] = h;
                    oc[(size_t)row * (2 * COUT) + COUT + col] = (f16)(v - (float)h);
                } else if (row == N) {            // write sentinel zero row
                    oc[(size_t)row * (2 * COUT) + col] = (f16)0.f;
                    oc[(size_t)row * (2 * COUT) + COUT + col] = (f16)0.f;
                }
            } else {
                if (row < N && col < OUTC)
                    out_f32[(size_t)row * OUTC + col] = acc[ct][r];
            }
        }
    }
}

// ===========================================================================
extern "C" void kernel_launch(void* const* d_in, const int* in_sizes, int n_in,
                              void* d_out, int out_size, void* d_ws, size_t ws_size,
                              hipStream_t stream)
{
    const float* feat1 = (const float*)d_in[0];
    const float* feat2 = (const float*)d_in[1];
    const float* feat3 = (const float*)d_in[2];
    const float* W1    = (const float*)d_in[3];
    const float* W1s   = (const float*)d_in[4];
    const float* W2    = (const float*)d_in[5];
    const float* W2s   = (const float*)d_in[6];
    const float* W3    = (const float*)d_in[7];
    const float* W3p   = (const float*)d_in[8];
    const float* W3s   = (const float*)d_in[9];
    const float* W3t   = (const float*)d_in[10];
    const int* nbr1    = (const int*)d_in[11];
    const int* nbr2    = (const int*)d_in[12];
    const int* nbr3    = (const int*)d_in[13];
    const int* parent2 = (const int*)d_in[14];
    const int* parent3 = (const int*)d_in[15];
    const int* coords1 = (const int*)d_in[16];
    const int* coords2 = (const int*)d_in[17];

    const int N1 = in_sizes[0] / 80;
    const int N2 = in_sizes[1] / 48;
    const int N3 = in_sizes[2] / 16;

    float* out = (float*)d_out;
    float* o_points = out;                              // [N3,10]
    float* o_ppn1   = o_points + (size_t)N3 * 10;       // [N1,6]
    float* o_ppn2   = o_ppn1 + (size_t)N1 * 6;          // [N2,6]
    float* o_mask1  = o_ppn2 + (size_t)N2 * 6;          // [N1]
    float* o_mask2  = o_mask1 + (size_t)N1;             // [N2]

    // ---- workspace (256B-aligned bump allocator) ----
    char* wp = (char*)d_ws;
    auto alloc = [&](size_t bytes) -> char* {
        char* r = wp; wp += (bytes + 255) & ~(size_t)255; return r;
    };
    f16* WT1  = (f16*)alloc((size_t)80 * 28 * 160 * 2);
    f16* WT1s = (f16*)alloc((size_t)16 * 28 * 160 * 2);
    f16* WT2  = (f16*)alloc((size_t)48 * 28 * 96 * 2);
    f16* WT2s = (f16*)alloc((size_t)16 * 28 * 96 * 2);
    f16* WT3  = (f16*)alloc((size_t)16 * 28 * 32 * 2);
    f16* WTp  = (f16*)alloc((size_t)16 * 28 * 32 * 2);
    float* s1 = (float*)alloc((size_t)N1 * 2 * 4);
    float* s2 = (float*)alloc((size_t)N2 * 2 * 4);
    size_t fe1 = (size_t)(N1 + 1) * 160, fe2 = (size_t)(N2 + 1) * 96, fe3 = (size_t)(N3 + 1) * 32;
    size_t maxF = fe1 > fe2 ? fe1 : fe2; if (fe3 > maxF) maxF = fe3;
    f16* Fa = (f16*)alloc(maxF * 2);    // input features (combined h|l + sentinel)
    f16* Ya = (f16*)alloc(maxF * 2);    // conv outputs y/z (combined h|l + sentinel)

    auto cdiv = [](long long a, long long b) { return (int)((a + b - 1) / b); };
    auto grid8 = [&](int nT) { return dim3(8 * cdiv(nT, 8)); };

    // ---- weight prep (one kernel) ----
    prep_all_kernel<<<1024, 256, 0, stream>>>(W1, WT1, W1s, WT1s, W2, WT2,
                                              W2s, WT2s, W3, WT3, W3p, W3s, W3t, WTp);

    // ---- level 1 (coarse, C=80): BM=128/512thr main, BM=64/256thr score ----
    {
        int T = cdiv(N1 + 1, 128), Ts = cdiv(N1 + 1, 64);
        split_feat_kernel<80><<<cdiv((size_t)(N1 + 1) * 80, 256), 256, 0, stream>>>(
            feat1, nullptr, nullptr, Fa, N1);
        mfma_conv<80, 5, 8, 80, true><<<grid8(T), 512, 0, stream>>>(
            Fa, nbr1, WT1, nullptr, Ya, N1, T);
        mfma_conv<80, 1, 4, 2, false><<<grid8(Ts), 256, 0, stream>>>(
            Ya, nbr1, WT1s, s1, nullptr, N1, Ts);
        ppn_finalize_kernel<<<cdiv(N1, 256), 256, 0, stream>>>(coords1, s1, o_ppn1, o_mask1, N1);
    }
    // ---- level 2 (mid, C=48): BM=64/256thr ----
    {
        int T = cdiv(N2 + 1, 64);
        split_feat_kernel<48><<<cdiv((size_t)(N2 + 1) * 48, 256), 256, 0, stream>>>(
            feat2, o_mask1, parent2, Fa, N2);
        mfma_conv<48, 3, 4, 48, true><<<grid8(T), 256, 0, stream>>>(
            Fa, nbr2, WT2, nullptr, Ya, N2, T);
        mfma_conv<48, 1, 4, 2, false><<<grid8(T), 256, 0, stream>>>(
            Ya, nbr2, WT2s, s2, nullptr, N2, T);
        ppn_finalize_kernel<<<cdiv(N2, 256), 256, 0, stream>>>(coords2, s2, o_ppn2, o_mask2, N2);
    }
    // ---- level 3 (fine, C=16): BM=64/256thr ----
    {
        int T = cdiv(N3 + 1, 64);
        split_feat_kernel<16><<<cdiv((size_t)(N3 + 1) * 16, 256), 256, 0, stream>>>(
            feat3, o_mask2, parent3, Fa, N3);
        mfma_conv<16, 1, 4, 16, true><<<grid8(T), 256, 0, stream>>>(
            Fa, nbr3, WT3, nullptr, Ya, N3, T);
        mfma_conv<16, 1, 4, 10, false><<<grid8(T), 256, 0, stream>>>(
            Ya, nbr3, WTp, o_points, nullptr, N3, T);
    }
}